// Round 1
// baseline (471.870 us; speedup 1.0000x reference)
//
#include <hip/hip_runtime.h>
#include <hip/hip_bf16.h>

// Only q-projection -> phi -> retrieve(S0,z0) -> Wo projection is live.
// (S_new/z_new are deleted in the reference; Wk/bk/Wv/bv are dead inputs.)

#define EPS 1e-6f

typedef __attribute__((ext_vector_type(8))) short short8;
typedef __attribute__((ext_vector_type(4))) float f32x4;

typedef __attribute__((address_space(3))) void lds_t;
typedef const __attribute__((address_space(1))) void gbl_t;

__device__ __forceinline__ unsigned short f2bf(float f) {
    unsigned int u = __float_as_uint(f);
    u += 0x7fffu + ((u >> 16) & 1u);   // round-to-nearest-even
    return (unsigned short)(u >> 16);
}

// ---------------- fp32 -> bf16 conversion, 8 elems/thread ----------------
__global__ void cvt_bf16_kernel(const float* __restrict__ in,
                                unsigned short* __restrict__ out, int n8) {
    for (int i = blockIdx.x * blockDim.x + threadIdx.x; i < n8;
         i += gridDim.x * blockDim.x) {
        float4 a = reinterpret_cast<const float4*>(in)[2 * i];
        float4 b = reinterpret_cast<const float4*>(in)[2 * i + 1];
        short8 v;
        v[0] = (short)f2bf(a.x); v[1] = (short)f2bf(a.y);
        v[2] = (short)f2bf(a.z); v[3] = (short)f2bf(a.w);
        v[4] = (short)f2bf(b.x); v[5] = (short)f2bf(b.y);
        v[6] = (short)f2bf(b.z); v[7] = (short)f2bf(b.w);
        reinterpret_cast<short8*>(out)[i] = v;
    }
}

// ---------------- m97-style 128x128 GEMM, C = A @ B^T ----------------
// A [M][K] bf16, Bw [N][K] bf16 (nn.Linear weight layout), K multiple of 32.
// EPI==0: C = phi(A@B^T + bias) stored bf16. EPI==1: C stored fp32, no bias.
template <int EPI>
__global__ void gemm_bt_kernel(const unsigned short* __restrict__ A,
                               const unsigned short* __restrict__ Bw,
                               const float* __restrict__ bias,
                               void* __restrict__ Cp,
                               int M, int N, int K) {
    __shared__ unsigned short Alds[128][32];
    __shared__ unsigned short Blds[128][32];
    const int tid = threadIdx.x;
    const int wave = tid >> 6, lane = tid & 63;
    const int wm = wave >> 1, wn = wave & 1;           // 2x2 waves, 64x64 each
    const int tm = blockIdx.y * 128, tn = blockIdx.x * 128;

    const int srow = lane >> 2;            // staging: row within 16-row chunk
    const int scol = (lane & 3) * 8;       // staging: k offset (8 bf16 = 16B)

    f32x4 acc[4][4] = {};

    for (int k0 = 0; k0 < K; k0 += 32) {
        // stage A,B tiles: 2 issues each, 256 thr x 16B = 4KB/issue
#pragma unroll
        for (int i = 0; i < 2; ++i) {
            const unsigned short* ga =
                A + (size_t)(tm + i * 64 + wave * 16 + srow) * K + (k0 + scol);
            __builtin_amdgcn_global_load_lds((gbl_t*)ga,
                (lds_t*)&Alds[i * 64 + wave * 16][0], 16, 0, 0);
            const unsigned short* gb =
                Bw + (size_t)(tn + i * 64 + wave * 16 + srow) * K + (k0 + scol);
            __builtin_amdgcn_global_load_lds((gbl_t*)gb,
                (lds_t*)&Blds[i * 64 + wave * 16][0], 16, 0, 0);
        }
        __syncthreads();   // drains vmcnt before barrier (compiler-inserted)

        short8 af[4], bfr[4];
#pragma unroll
        for (int mi = 0; mi < 4; ++mi)
            af[mi] = *reinterpret_cast<const short8*>(
                &Alds[wm * 64 + mi * 16 + (lane & 15)][(lane >> 4) * 8]);
#pragma unroll
        for (int ni = 0; ni < 4; ++ni)
            bfr[ni] = *reinterpret_cast<const short8*>(
                &Blds[wn * 64 + ni * 16 + (lane & 15)][(lane >> 4) * 8]);
#pragma unroll
        for (int mi = 0; mi < 4; ++mi)
#pragma unroll
            for (int ni = 0; ni < 4; ++ni)
                acc[mi][ni] = __builtin_amdgcn_mfma_f32_16x16x32_bf16(
                    af[mi], bfr[ni], acc[mi][ni], 0, 0, 0);
        __syncthreads();   // protect LDS before next-iter overwrite
    }

#pragma unroll
    for (int mi = 0; mi < 4; ++mi)
#pragma unroll
        for (int ni = 0; ni < 4; ++ni)
#pragma unroll
            for (int j = 0; j < 4; ++j) {
                int r = tm + wm * 64 + mi * 16 + (lane >> 4) * 4 + j;
                int c = tn + wn * 64 + ni * 16 + (lane & 15);
                float v = acc[mi][ni][j];
                if (EPI == 0) {
                    v += bias[c];
                    v = v > 0.f ? v + 1.f : __expf(v);  // elu(x)+1
                    ((unsigned short*)Cp)[(size_t)r * N + c] = f2bf(v);
                } else {
                    ((float*)Cp)[(size_t)r * N + c] = v;
                }
            }
}

// ---------------- retrieve: mid = (qf @ S0) / (qf . z0 + eps) ----------------
// qf [B*S][1024] bf16; per (b,h) uses 64-col slice. Block: one (b,h) x 256 rows.
__global__ void retrieve_kernel(const unsigned short* __restrict__ qf,
                                const float* __restrict__ S0,
                                const float* __restrict__ z0,
                                unsigned short* __restrict__ mid) {
    __shared__ unsigned short Bt[64][72];  // Bt[e][d] = bf16(S0[d][e]); +8 pad
    const int tid = threadIdx.x;
    const int wave = tid >> 6, lane = tid & 63;
    const int bh = blockIdx.y;             // b*16 + h
    const int b = bh >> 4, h = bh & 15;

    const float* S = S0 + (size_t)bh * 4096;
#pragma unroll
    for (int it = 0; it < 16; ++it) {
        int idx = it * 256 + tid;
        int d = idx >> 6, e = idx & 63;
        Bt[e][d] = f2bf(S[idx]);           // coalesced read, scattered LDS write
    }
    // z0 broadcast B-fragment: B'[k][c] = z0[k] for all c
    const float* z = z0 + bh * 64;
    short8 zf[2];
#pragma unroll
    for (int ks = 0; ks < 2; ++ks)
#pragma unroll
        for (int i = 0; i < 8; ++i)
            zf[ks][i] = (short)f2bf(z[ks * 32 + (lane >> 4) * 8 + i]);
    __syncthreads();

    const int srow0 = blockIdx.x * 256 + wave * 64;
    f32x4 num[4][4] = {};
    f32x4 den[4] = {};
#pragma unroll
    for (int ks = 0; ks < 2; ++ks) {
        short8 af[4];
#pragma unroll
        for (int mi = 0; mi < 4; ++mi) {
            size_t row = (size_t)b * 8192 + srow0 + mi * 16 + (lane & 15);
            af[mi] = *reinterpret_cast<const short8*>(
                &qf[row * 1024 + h * 64 + ks * 32 + (lane >> 4) * 8]);
        }
#pragma unroll
        for (int mi = 0; mi < 4; ++mi) {
#pragma unroll
            for (int ni = 0; ni < 4; ++ni) {
                short8 bfr = *reinterpret_cast<const short8*>(
                    &Bt[ni * 16 + (lane & 15)][ks * 32 + (lane >> 4) * 8]);
                num[mi][ni] = __builtin_amdgcn_mfma_f32_16x16x32_bf16(
                    af[mi], bfr, num[mi][ni], 0, 0, 0);
            }
            den[mi] = __builtin_amdgcn_mfma_f32_16x16x32_bf16(
                af[mi], zf[ks], den[mi], 0, 0, 0);  // den rows == acc rows
        }
    }
#pragma unroll
    for (int mi = 0; mi < 4; ++mi)
#pragma unroll
        for (int ni = 0; ni < 4; ++ni)
#pragma unroll
            for (int j = 0; j < 4; ++j) {
                size_t row = (size_t)b * 8192 + srow0 + mi * 16 + (lane >> 4) * 4 + j;
                int c = h * 64 + ni * 16 + (lane & 15);
                float v = num[mi][ni][j] / (den[mi][j] + EPS);
                mid[row * 1024 + c] = f2bf(v);
            }
}

extern "C" void kernel_launch(void* const* d_in, const int* in_sizes, int n_in,
                              void* d_out, int out_size, void* d_ws, size_t ws_size,
                              hipStream_t stream) {
    const float* X  = (const float*)d_in[0];
    const float* Wq = (const float*)d_in[1];
    const float* bq = (const float*)d_in[2];
    const float* Wo = (const float*)d_in[7];
    const float* S0 = (const float*)d_in[8];
    const float* z0 = (const float*)d_in[9];
    float* out = (float*)d_out;

    // workspace: Xb (67MB, reused as mid) | qf (67MB) | Wqb (2MB) | Wob (2MB)
    char* ws = (char*)d_ws;
    unsigned short* Xb  = (unsigned short*)ws;
    unsigned short* qf  = (unsigned short*)(ws + 67108864);
    unsigned short* Wqb = (unsigned short*)(ws + 134217728);
    unsigned short* Wob = (unsigned short*)(ws + 136314880);

    cvt_bf16_kernel<<<2048, 256, 0, stream>>>(X,  Xb,  33554432 / 8);
    cvt_bf16_kernel<<<512,  256, 0, stream>>>(Wq, Wqb, 1048576 / 8);
    cvt_bf16_kernel<<<512,  256, 0, stream>>>(Wo, Wob, 1048576 / 8);

    dim3 g(8, 256);  // N/128, M/128
    gemm_bt_kernel<0><<<g, 256, 0, stream>>>(Xb, Wqb, bq, qf, 32768, 1024, 1024);
    retrieve_kernel<<<dim3(32, 64), 256, 0, stream>>>(qf, S0, z0, Xb /*mid*/);
    gemm_bt_kernel<1><<<g, 256, 0, stream>>>(Xb, Wob, nullptr, out, 32768, 1024, 1024);
}

// Round 2
// 428.577 us; speedup vs baseline: 1.1010x; 1.1010x over previous
//
#include <hip/hip_runtime.h>
#include <hip/hip_bf16.h>

// Live computation: q = X@Wq.T+bq -> phi -> mid = (phi@S0)/(phi.z0+eps) -> out = mid@Wo.T
// (S_new/z_new are dead in the reference; Wk/bk/Wv/bv unused.)
// GEMM1 tile is 128 cols = exactly 2 heads -> retrieve fused into its epilogue.

#define EPS 1e-6f

typedef __attribute__((ext_vector_type(8))) short short8;
typedef __attribute__((ext_vector_type(4))) float f32x4;

typedef __attribute__((address_space(3))) void lds_t;
typedef const __attribute__((address_space(1))) void gbl_t;

__device__ __forceinline__ unsigned short f2bf(float f) {
    unsigned int u = __float_as_uint(f);
    u += 0x7fffu + ((u >> 16) & 1u);   // round-to-nearest-even
    return (unsigned short)(u >> 16);
}

// ---------------- fp32 -> bf16 conversion, 8 elems/thread ----------------
__global__ void cvt_bf16_kernel(const float* __restrict__ in,
                                unsigned short* __restrict__ out, int n8) {
    for (int i = blockIdx.x * blockDim.x + threadIdx.x; i < n8;
         i += gridDim.x * blockDim.x) {
        float4 a = reinterpret_cast<const float4*>(in)[2 * i];
        float4 b = reinterpret_cast<const float4*>(in)[2 * i + 1];
        short8 v;
        v[0] = (short)f2bf(a.x); v[1] = (short)f2bf(a.y);
        v[2] = (short)f2bf(a.z); v[3] = (short)f2bf(a.w);
        v[4] = (short)f2bf(b.x); v[5] = (short)f2bf(b.y);
        v[6] = (short)f2bf(b.z); v[7] = (short)f2bf(b.w);
        reinterpret_cast<short8*>(out)[i] = v;
    }
}

// Both weight matrices in one launch. Grid sized so i covers exactly 2*n8.
__global__ void cvt_w_kernel(const float* __restrict__ w0,
                             const float* __restrict__ w1,
                             unsigned short* __restrict__ o0,
                             unsigned short* __restrict__ o1, int n8) {
    int i = blockIdx.x * blockDim.x + threadIdx.x;
    const float* in = (i < n8) ? w0 : w1;
    unsigned short* out = (i < n8) ? o0 : o1;
    int j = (i < n8) ? i : i - n8;
    float4 a = reinterpret_cast<const float4*>(in)[2 * j];
    float4 b = reinterpret_cast<const float4*>(in)[2 * j + 1];
    short8 v;
    v[0] = (short)f2bf(a.x); v[1] = (short)f2bf(a.y);
    v[2] = (short)f2bf(a.z); v[3] = (short)f2bf(a.w);
    v[4] = (short)f2bf(b.x); v[5] = (short)f2bf(b.y);
    v[6] = (short)f2bf(b.z); v[7] = (short)f2bf(b.w);
    reinterpret_cast<short8*>(out)[j] = v;
}

// stage one 128x32 A-tile and B-tile half into LDS buffer `buf` (async, vmcnt)
#define STAGE(AL, BL, buf, k0)                                                   \
    {                                                                            \
        _Pragma("unroll")                                                        \
        for (int i_ = 0; i_ < 2; ++i_) {                                         \
            const unsigned short* ga_ =                                          \
                A + (size_t)(tm + i_ * 64 + wave * 16 + srow) * 1024 + ((k0) + scol); \
            __builtin_amdgcn_global_load_lds((gbl_t*)ga_,                        \
                (lds_t*)&AL[buf][i_ * 64 + wave * 16][0], 16, 0, 0);             \
            const unsigned short* gb_ =                                          \
                Bw + (size_t)(tn + i_ * 64 + wave * 16 + srow) * 1024 + ((k0) + scol); \
            __builtin_amdgcn_global_load_lds((gbl_t*)gb_,                        \
                (lds_t*)&BL[buf][i_ * 64 + wave * 16][0], 16, 0, 0);             \
        }                                                                        \
    }

// ------- GEMM1 fused: mid = phi(X@Wq.T + bq) retrieved against (S0, z0) -------
// 128x128 tile, 2x2 waves, BK=32, double-buffered staging, XCD-chunked swizzle.
__global__ __launch_bounds__(256, 3)
void gemm_qs_kernel(const unsigned short* __restrict__ A,    // Xb [32768][1024]
                    const unsigned short* __restrict__ Bw,   // Wqb [1024][1024]
                    const float* __restrict__ bias,          // bq
                    const float* __restrict__ S0,            // [4*16][64][64]
                    const float* __restrict__ z0,            // [4*16][64]
                    unsigned short* __restrict__ mid) {
    __shared__ union {
        struct {
            unsigned short Alds[2][128][32];
            unsigned short Blds[2][128][32];
        } s;                                   // 32 KB (K-loop)
        unsigned short Q[128][136];            // 34.8 KB (epilogue, +8 pad)
    } u;
    __shared__ unsigned short S0t[2][64][72];  // S0^T per head, bf16, +8 pad

    const int tid = threadIdx.x;
    const int wave = tid >> 6, lane = tid & 63;
    const int wm = wave >> 1, wn = wave & 1;   // 2x2 waves, 64x64 each

    // XCD-chunked swizzle: nwg=2048, 8 XCDs, 256 blocks/XCD contiguous work
    const int bid = blockIdx.y * gridDim.x + blockIdx.x;
    const int swz = (bid & 7) * 256 + (bid >> 3);
    const int bx = swz & 7, by = swz >> 3;
    const int tm = by * 128, tn = bx * 128;
    const int b = by >> 6;                     // batch (8192 rows each)
    const int h0 = bx * 2;                     // tile covers heads h0, h0+1

    const int srow = lane >> 2;                // staging row within 16-row chunk
    const int scol = (lane & 3) * 8;           // staging k offset (16B)

    // stage S0^T for the two heads: S0t[hh][e][d] = bf16(S0[b,h0+hh][d][e])
#pragma unroll
    for (int hh = 0; hh < 2; ++hh) {
        const float* S = S0 + (size_t)(b * 16 + h0 + hh) * 4096;
#pragma unroll
        for (int it = 0; it < 16; ++it) {
            int idx = it * 256 + tid;
            S0t[hh][idx & 63][idx >> 6] = f2bf(S[idx]);
        }
    }
    // z0-broadcast B-fragment for this wave's head (den rows == num acc rows)
    const float* z = z0 + (b * 16 + h0 + wn) * 64;
    short8 zf[2];
#pragma unroll
    for (int ks = 0; ks < 2; ++ks)
#pragma unroll
        for (int i = 0; i < 8; ++i)
            zf[ks][i] = (short)f2bf(z[ks * 32 + (lane >> 4) * 8 + i]);
    // bias for this wave's 4 output col-fragments
    float bv[4];
#pragma unroll
    for (int ni = 0; ni < 4; ++ni)
        bv[ni] = bias[tn + wn * 64 + ni * 16 + (lane & 15)];

    f32x4 acc[4][4] = {};
    STAGE(u.s.Alds, u.s.Blds, 0, 0);
    __syncthreads();

    for (int t = 0; t < 32; ++t) {
        if (t < 31) STAGE(u.s.Alds, u.s.Blds, (t + 1) & 1, (t + 1) * 32);
        const int buf = t & 1;
        short8 af[4], bfr[4];
#pragma unroll
        for (int mi = 0; mi < 4; ++mi)
            af[mi] = *reinterpret_cast<const short8*>(
                &u.s.Alds[buf][wm * 64 + mi * 16 + (lane & 15)][(lane >> 4) * 8]);
#pragma unroll
        for (int ni = 0; ni < 4; ++ni)
            bfr[ni] = *reinterpret_cast<const short8*>(
                &u.s.Blds[buf][wn * 64 + ni * 16 + (lane & 15)][(lane >> 4) * 8]);
#pragma unroll
        for (int mi = 0; mi < 4; ++mi)
#pragma unroll
            for (int ni = 0; ni < 4; ++ni)
                acc[mi][ni] = __builtin_amdgcn_mfma_f32_16x16x32_bf16(
                    af[mi], bfr[ni], acc[mi][ni], 0, 0, 0);
        __syncthreads();  // staging of buf^1 done, everyone done reading buf
    }

    // epilogue part 1: qf = phi(acc + bias) -> LDS (reuses staging space)
#pragma unroll
    for (int mi = 0; mi < 4; ++mi)
#pragma unroll
        for (int ni = 0; ni < 4; ++ni) {
            const int lc = wn * 64 + ni * 16 + (lane & 15);
#pragma unroll
            for (int j = 0; j < 4; ++j) {
                const int lr = wm * 64 + mi * 16 + (lane >> 4) * 4 + j;
                float v = acc[mi][ni][j] + bv[ni];
                v = v > 0.f ? v + 1.f : __expf(v);   // elu(x)+1
                u.Q[lr][lc] = f2bf(v);
            }
        }
    __syncthreads();

    // epilogue part 2: num = qf @ S0, den = qf . z0 (wave wn owns head h0+wn)
    f32x4 o2[4][4] = {};
    f32x4 d2[4] = {};
#pragma unroll
    for (int ks = 0; ks < 2; ++ks) {
        short8 af2[4];
#pragma unroll
        for (int mi = 0; mi < 4; ++mi)
            af2[mi] = *reinterpret_cast<const short8*>(
                &u.Q[wm * 64 + mi * 16 + (lane & 15)][wn * 64 + ks * 32 + (lane >> 4) * 8]);
#pragma unroll
        for (int mi = 0; mi < 4; ++mi) {
#pragma unroll
            for (int ni = 0; ni < 4; ++ni) {
                short8 b2 = *reinterpret_cast<const short8*>(
                    &S0t[wn][ni * 16 + (lane & 15)][ks * 32 + (lane >> 4) * 8]);
                o2[mi][ni] = __builtin_amdgcn_mfma_f32_16x16x32_bf16(
                    af2[mi], b2, o2[mi][ni], 0, 0, 0);
            }
            d2[mi] = __builtin_amdgcn_mfma_f32_16x16x32_bf16(
                af2[mi], zf[ks], d2[mi], 0, 0, 0);
        }
    }
#pragma unroll
    for (int mi = 0; mi < 4; ++mi)
#pragma unroll
        for (int ni = 0; ni < 4; ++ni)
#pragma unroll
            for (int j = 0; j < 4; ++j) {
                size_t gr = (size_t)tm + wm * 64 + mi * 16 + (lane >> 4) * 4 + j;
                int gc = tn + wn * 64 + ni * 16 + (lane & 15);
                mid[gr * 1024 + gc] = f2bf(o2[mi][ni][j] / (d2[mi][j] + EPS));
            }
}

// ---------------- GEMM2: out = mid @ Wo.T (fp32 out, no bias) ----------------
__global__ void gemm_o_kernel(const unsigned short* __restrict__ A,   // mid bf16
                              const unsigned short* __restrict__ Bw,  // Wob
                              float* __restrict__ out) {
    __shared__ unsigned short Alds[2][128][32];
    __shared__ unsigned short Blds[2][128][32];
    const int tid = threadIdx.x;
    const int wave = tid >> 6, lane = tid & 63;
    const int wm = wave >> 1, wn = wave & 1;

    const int bid = blockIdx.y * gridDim.x + blockIdx.x;
    const int swz = (bid & 7) * 256 + (bid >> 3);
    const int bx = swz & 7, by = swz >> 3;
    const int tm = by * 128, tn = bx * 128;

    const int srow = lane >> 2;
    const int scol = (lane & 3) * 8;

    f32x4 acc[4][4] = {};
    STAGE(Alds, Blds, 0, 0);
    __syncthreads();

    for (int t = 0; t < 32; ++t) {
        if (t < 31) STAGE(Alds, Blds, (t + 1) & 1, (t + 1) * 32);
        const int buf = t & 1;
        short8 af[4], bfr[4];
#pragma unroll
        for (int mi = 0; mi < 4; ++mi)
            af[mi] = *reinterpret_cast<const short8*>(
                &Alds[buf][wm * 64 + mi * 16 + (lane & 15)][(lane >> 4) * 8]);
#pragma unroll
        for (int ni = 0; ni < 4; ++ni)
            bfr[ni] = *reinterpret_cast<const short8*>(
                &Blds[buf][wn * 64 + ni * 16 + (lane & 15)][(lane >> 4) * 8]);
#pragma unroll
        for (int mi = 0; mi < 4; ++mi)
#pragma unroll
            for (int ni = 0; ni < 4; ++ni)
                acc[mi][ni] = __builtin_amdgcn_mfma_f32_16x16x32_bf16(
                    af[mi], bfr[ni], acc[mi][ni], 0, 0, 0);
        __syncthreads();
    }

#pragma unroll
    for (int mi = 0; mi < 4; ++mi)
#pragma unroll
        for (int ni = 0; ni < 4; ++ni)
#pragma unroll
            for (int j = 0; j < 4; ++j) {
                size_t gr = (size_t)tm + wm * 64 + mi * 16 + (lane >> 4) * 4 + j;
                int gc = tn + wn * 64 + ni * 16 + (lane & 15);
                out[gr * 1024 + gc] = acc[mi][ni][j];
            }
}

extern "C" void kernel_launch(void* const* d_in, const int* in_sizes, int n_in,
                              void* d_out, int out_size, void* d_ws, size_t ws_size,
                              hipStream_t stream) {
    const float* X  = (const float*)d_in[0];
    const float* Wq = (const float*)d_in[1];
    const float* bq = (const float*)d_in[2];
    const float* Wo = (const float*)d_in[7];
    const float* S0 = (const float*)d_in[8];
    const float* z0 = (const float*)d_in[9];
    float* out = (float*)d_out;

    // workspace: Xb (67MB) | mid (67MB) | Wqb (2MB) | Wob (2MB)
    char* ws = (char*)d_ws;
    unsigned short* Xb  = (unsigned short*)ws;
    unsigned short* mid = (unsigned short*)(ws + 67108864);
    unsigned short* Wqb = (unsigned short*)(ws + 134217728);
    unsigned short* Wob = (unsigned short*)(ws + 136314880);

    cvt_bf16_kernel<<<2048, 256, 0, stream>>>(X, Xb, 33554432 / 8);
    cvt_w_kernel<<<1024, 256, 0, stream>>>(Wq, Wo, Wqb, Wob, 1048576 / 8);

    dim3 g(8, 256);  // N/128, M/128 (as hw ids; work remapped by XCD swizzle)
    gemm_qs_kernel<<<g, 256, 0, stream>>>(Xb, Wqb, bq, S0, z0, mid);
    gemm_o_kernel<<<g, 256, 0, stream>>>(mid, Wob, out);
}